// Round 1
// baseline (972.091 us; speedup 1.0000x reference)
//
#include <hip/hip_runtime.h>

// Problem constants
#define BN 65536          // batch
#define NT 256            // threads per block
#define NCELL 72          // 12x6 trimmed board
// ws layout (float offsets)
#define OFF_M    0                       // 4 * 5184  (MT[mat][t][o], mat: 0=each,1=not,2=not2,3=empty)
#define OFF_W1T  20736                   // 72*100
#define OFF_W2T  27936                   // 100*100
#define OFF_ACV  40960                   // 72*BN   (acv2 / x)
#define OFF_S    (40960 + 72*BN)         // 72*BN   (S = empty + ecv_sel)
#define OFF_Z    (OFF_S + 72*BN)         // 12*BN u32 (z bits, 3 words per kind 1..4)
#define OFF_MK   (OFF_Z + 12*BN)         // 15*BN u32 (mask bits, 3 words per kind 0..4)
#define OFF_H1   OFF_S                   // 100*BN  (overlaps S/Z/MK - dead by then)
// total ws floats = OFF_S + 100*BN = 11,313,152  (~45.3 MB)

// ---------------- precompute: conv matrices + transposed FC weights ----------------
__global__ __launch_bounds__(NT) void k_pre(
    const float* __restrict__ w_each, const float* __restrict__ w_not,
    const float* __restrict__ w_not2, const float* __restrict__ w_empty,
    const float* __restrict__ W1, const float* __restrict__ W2,
    float* __restrict__ ws)
{
  int i = blockIdx.x * NT + threadIdx.x;
  if (i < 4 * 5184) {
    int m = i / 5184, r = i - m * 5184;
    int t = r / 72, o = r - t * 72;
    int hi = t / 6, wi = t - 6 * (t / 6);
    int ho = o / 6, wo = o - 6 * (o / 6);
    int dr = hi - ho + 6, dc = wi - wo + 6;
    const float* w = (m == 0) ? w_each : (m == 1) ? w_not : (m == 2) ? w_not2 : w_empty;
    ws[i] = (dr >= 0 && dr < 13) ? w[dr * 13 + dc] : 0.f;
  } else if (i < 4 * 5184 + 7200) {
    int j = i - 4 * 5184;
    int t = j / 100, o = j - 100 * t;        // W1T[t*100+o] = W1[o*72+t]
    ws[OFF_W1T + j] = W1[o * 72 + t];
  } else if (i < 4 * 5184 + 7200 + 10000) {
    int j = i - 4 * 5184 - 7200;
    int t = j / 100, o = j - 100 * t;        // W2T[t*100+o] = W2[o*100+t]
    ws[OFF_W2T + j] = W2[o * 100 + t];
  }
}

// ---------------- build per-batch kind bitmasks ----------------
__global__ __launch_bounds__(NT) void k_masks(const int* __restrict__ dots,
                                              unsigned* __restrict__ MK)
{
  int b = blockIdx.x * NT + threadIdx.x;
  unsigned mk[5][3] = {{0,0,0},{0,0,0},{0,0,0},{0,0,0},{0,0,0}};
#pragma unroll
  for (int c = 0; c < NCELL; ++c) {
    int v = dots[c * BN + b];
#pragma unroll
    for (int k = 0; k < 5; ++k)
      mk[k][c >> 5] |= (unsigned)(v == k) << (c & 31);
  }
#pragma unroll
  for (int k = 0; k < 5; ++k)
#pragma unroll
    for (int j = 0; j < 3; ++j)
      MK[(k * 3 + j) * BN + b] = mk[k][j];
}

// conv of a binary (bitmask) input: acc[o] = binit + sum_t M[t][o]*bit(t)
__device__ __forceinline__ void conv_bits(float (&acc)[NCELL],
                                          unsigned i0, unsigned i1, unsigned i2,
                                          const float* __restrict__ Mt, float binit)
{
#pragma unroll
  for (int o = 0; o < NCELL; ++o) acc[o] = binit;
#pragma unroll
  for (int t = 0; t < NCELL; ++t) {
    unsigned w = (t < 32) ? i0 : (t < 64) ? i1 : i2;
    float x = (float)((w >> (t & 31)) & 1u);
#pragma unroll
    for (int o = 0; o < NCELL; ++o)
      acc[o] = fmaf(Mt[t * 72 + o], x, acc[o]);
  }
}

// ---------------- pass 1: empty conv, z bits, ecv convs -> S, not convs -> acv_init ----------------
__global__ __launch_bounds__(NT) void k1(
    const float* __restrict__ M, const unsigned* __restrict__ MK,
    unsigned* __restrict__ Z, float* __restrict__ Sws, float* __restrict__ ACV,
    const float* __restrict__ b_each, const float* __restrict__ b_not,
    const float* __restrict__ b_empty)
{
  int b = blockIdx.x * NT + threadIdx.x;
  float bea = *b_each, bno = *b_not, bem = *b_empty;
  float S[NCELL], acc[NCELL];

  // phase A: c=0 (empty mask) then c=1..4 (kind masks)
#pragma unroll 1
  for (int c = 0; c < 5; ++c) {
    unsigned i0 = MK[(c * 3 + 0) * BN + b];
    unsigned i1 = MK[(c * 3 + 1) * BN + b];
    unsigned i2 = MK[(c * 3 + 2) * BN + b];
    const float* Mb = (c == 0) ? (M + 3 * 5184) : M;  // empty-mat else each-mat
    float binit = (c == 0) ? bem : bea;
    conv_bits(acc, i0, i1, i2, Mb, binit);
    if (c == 0) {
#pragma unroll
      for (int t = 0; t < NCELL; ++t) S[t] = acc[t];  // S = empty
      // z_k bits: (mask_k + empty) > 0
#pragma unroll
      for (int k = 1; k <= 4; ++k) {
        unsigned m0 = MK[(k * 3 + 0) * BN + b];
        unsigned m1 = MK[(k * 3 + 1) * BN + b];
        unsigned m2 = MK[(k * 3 + 2) * BN + b];
        unsigned z0 = 0, z1 = 0, z2 = 0;
#pragma unroll
        for (int t = 0; t < NCELL; ++t) {
          unsigned w = (t < 32) ? m0 : (t < 64) ? m1 : m2;
          float mf = (float)((w >> (t & 31)) & 1u);
          unsigned zb = ((acc[t] + mf) > 0.f) ? 1u : 0u;
          if (t < 32) z0 |= zb << t;
          else if (t < 64) z1 |= zb << (t - 32);
          else z2 |= zb << (t - 64);
        }
        Z[((k - 1) * 3 + 0) * BN + b] = z0;
        Z[((k - 1) * 3 + 1) * BN + b] = z1;
        Z[((k - 1) * 3 + 2) * BN + b] = z2;
      }
    } else {
      // S += ecv_k at kind==k cells (acc already includes b_each)
#pragma unroll
      for (int t = 0; t < NCELL; ++t) {
        unsigned w = (t < 32) ? i0 : (t < 64) ? i1 : i2;
        if ((w >> (t & 31)) & 1u) S[t] += acc[t];
      }
    }
  }
  // write S (= empty + ecv_sel)
#pragma unroll
  for (int t = 0; t < NCELL; ++t) Sws[t * BN + b] = S[t];

  // phase B: not-convs; input = ~z_k; acv contribution at kind==k cells: S - not_conv
#pragma unroll 1
  for (int k = 1; k <= 4; ++k) {
    unsigned z0 = ~Z[((k - 1) * 3 + 0) * BN + b];
    unsigned z1 = ~Z[((k - 1) * 3 + 1) * BN + b];
    unsigned z2 = ~Z[((k - 1) * 3 + 2) * BN + b];
    conv_bits(acc, z0, z1, z2, M + 1 * 5184, bno);
    unsigned m0 = MK[(k * 3 + 0) * BN + b];
    unsigned m1 = MK[(k * 3 + 1) * BN + b];
    unsigned m2 = MK[(k * 3 + 2) * BN + b];
#pragma unroll
    for (int t = 0; t < NCELL; ++t) {
      unsigned w = (t < 32) ? m0 : (t < 64) ? m1 : m2;
      if ((w >> (t & 31)) & 1u) S[t] -= acc[t];   // S-reg becomes acv at kind cells
    }
  }
  // empty cells -> 0; write acv2 init
  unsigned e0 = MK[0 * BN + b], e1 = MK[1 * BN + b], e2 = MK[2 * BN + b];
#pragma unroll
  for (int t = 0; t < NCELL; ++t) {
    unsigned w = (t < 32) ? e0 : (t < 64) ? e1 : e2;
    float v = ((w >> (t & 31)) & 1u) ? 0.f : S[t];
    ACV[t * BN + b] = v;
  }
}

// ---------------- pass 2: 4 sequential not2-convs updating acv2 ----------------
__global__ __launch_bounds__(NT) void k2(
    const float* __restrict__ M, const unsigned* __restrict__ MK,
    const unsigned* __restrict__ Z, const float* __restrict__ Sws,
    float* __restrict__ ACV, const float* __restrict__ b_not2)
{
  int b = blockIdx.x * NT + threadIdx.x;
  float bn2 = *b_not2;
  float S[NCELL], acv[NCELL], acc[NCELL];
#pragma unroll
  for (int t = 0; t < NCELL; ++t) {
    S[t] = Sws[t * BN + b];
    acv[t] = ACV[t * BN + b];
  }
  const float* Mt = M + 2 * 5184;   // not2-mat
#pragma unroll 1
  for (int k = 1; k <= 4; ++k) {
    unsigned z0 = Z[((k - 1) * 3 + 0) * BN + b];
    unsigned z1 = Z[((k - 1) * 3 + 1) * BN + b];
    unsigned z2 = Z[((k - 1) * 3 + 2) * BN + b];
#pragma unroll
    for (int o = 0; o < NCELL; ++o) acc[o] = bn2;
#pragma unroll
    for (int t = 0; t < NCELL; ++t) {
      unsigned w = (t < 32) ? z0 : (t < 64) ? z1 : z2;
      float x = ((w >> (t & 31)) & 1u) ? 0.f : acv[t];   // not2 = z ? 0 : acv2
#pragma unroll
      for (int o = 0; o < NCELL; ++o)
        acc[o] = fmaf(Mt[t * 72 + o], x, acc[o]);
    }
    unsigned m0 = MK[(k * 3 + 0) * BN + b];
    unsigned m1 = MK[(k * 3 + 1) * BN + b];
    unsigned m2 = MK[(k * 3 + 2) * BN + b];
#pragma unroll
    for (int t = 0; t < NCELL; ++t) {
      unsigned w = (t < 32) ? m0 : (t < 64) ? m1 : m2;
      if ((w >> (t & 31)) & 1u) acv[t] += S[t] + acc[t];  // v = S + conv(not2)
    }
  }
#pragma unroll
  for (int t = 0; t < NCELL; ++t) ACV[t * BN + b] = acv[t];
}

// ---------------- FC1: x[72] -> h1[100] (leaky relu) ----------------
__global__ __launch_bounds__(NT) void k3(
    const float* __restrict__ W1T, const float* __restrict__ X,
    float* __restrict__ H1, const float* __restrict__ b1)
{
  int b = blockIdx.x * NT + threadIdx.x;
  float h[100];
#pragma unroll
  for (int o = 0; o < 100; ++o) h[o] = b1[o];
#pragma unroll 1
  for (int t = 0; t < NCELL; ++t) {
    float x = X[t * BN + b];
    const float* r = W1T + t * 100;
#pragma unroll
    for (int o = 0; o < 100; ++o) h[o] = fmaf(r[o], x, h[o]);
  }
#pragma unroll
  for (int o = 0; o < 100; ++o) {
    float v = h[o];
    v = fmaxf(v, 0.2f * v);          // leaky_relu 0.2
    H1[o * BN + b] = v;
  }
}

// ---------------- FC2 + FC3: h1 -> h2 (leaky relu) -> scalar out ----------------
__global__ __launch_bounds__(NT) void k4(
    const float* __restrict__ W2T, const float* __restrict__ H1,
    float* __restrict__ out, const float* __restrict__ b2,
    const float* __restrict__ W3, const float* __restrict__ b3)
{
  int b = blockIdx.x * NT + threadIdx.x;
  float h[100];
#pragma unroll
  for (int o = 0; o < 100; ++o) h[o] = b2[o];
#pragma unroll 1
  for (int t = 0; t < 100; ++t) {
    float x = H1[t * BN + b];
    const float* r = W2T + t * 100;
#pragma unroll
    for (int o = 0; o < 100; ++o) h[o] = fmaf(r[o], x, h[o]);
  }
  float o0 = *b3;
#pragma unroll
  for (int j = 0; j < 100; ++j) {
    float v = h[j];
    v = fmaxf(v, 0.2f * v);
    o0 = fmaf(W3[j], v, o0);
  }
  out[b] = o0;
}

extern "C" void kernel_launch(void* const* d_in, const int* in_sizes, int n_in,
                              void* d_out, int out_size, void* d_ws, size_t ws_size,
                              hipStream_t stream)
{
  const int*   dots    = (const int*)d_in[0];
  const float* w_each  = (const float*)d_in[1];
  const float* b_each  = (const float*)d_in[2];
  const float* w_not   = (const float*)d_in[3];
  const float* b_not   = (const float*)d_in[4];
  const float* w_not2  = (const float*)d_in[5];
  const float* b_not2  = (const float*)d_in[6];
  const float* w_empty = (const float*)d_in[7];
  const float* b_empty = (const float*)d_in[8];
  const float* W1 = (const float*)d_in[9];
  const float* b1 = (const float*)d_in[10];
  const float* W2 = (const float*)d_in[11];
  const float* b2 = (const float*)d_in[12];
  const float* W3 = (const float*)d_in[13];
  const float* b3 = (const float*)d_in[14];

  float* ws = (float*)d_ws;
  float* outp = (float*)d_out;

  float*    Sws = ws + OFF_S;
  float*    ACV = ws + OFF_ACV;
  unsigned* Z   = (unsigned*)(ws + OFF_Z);
  unsigned* MK  = (unsigned*)(ws + OFF_MK);
  float*    H1  = ws + OFF_H1;

  (void)in_sizes; (void)n_in; (void)out_size; (void)ws_size;

  k_pre<<<(4 * 5184 + 7200 + 10000 + NT - 1) / NT, NT, 0, stream>>>(
      w_each, w_not, w_not2, w_empty, W1, W2, ws);
  k_masks<<<BN / NT, NT, 0, stream>>>(dots, MK);
  k1<<<BN / NT, NT, 0, stream>>>(ws, MK, Z, Sws, ACV, b_each, b_not, b_empty);
  k2<<<BN / NT, NT, 0, stream>>>(ws, MK, Z, Sws, ACV, b_not2);
  k3<<<BN / NT, NT, 0, stream>>>(ws + OFF_W1T, ACV, H1, b1);
  k4<<<BN / NT, NT, 0, stream>>>(ws + OFF_W2T, H1, outp, b2, W3, b3);
}

// Round 5
// 599.401 us; speedup vs baseline: 1.6218x; 1.6218x over previous
//
#include <hip/hip_runtime.h>

#define BN 65536
#define NT 128
#define NBLK (BN / NT)     // 512 blocks -> 2 blocks/CU, 1 wave/SIMD
#define NC 72

// LDS float buffer: 15552 floats = 62208 B (< 64 KB)
// phase A/B: sM[3][5184]: each @0, not @5184, empty @10368
// phase C  : acvL[72][128] @0 (9216), not2 @9216 (5184) -> 14400
// phase D  : acvL @0 + W1T half (36 rows x 100) @9216 (3600)
// phase E  : h1L[100][128] @0 (12800), W2T chunk (25 rows x 100) @12800 (2500)

__device__ __forceinline__ void fma_row72(float (&acc)[NC], const float* p, float x)
{
#pragma unroll
  for (int q = 0; q < 18; ++q) {
    float4 r = ((const float4*)p)[q];
    acc[4*q+0] = fmaf(r.x, x, acc[4*q+0]);
    acc[4*q+1] = fmaf(r.y, x, acc[4*q+1]);
    acc[4*q+2] = fmaf(r.z, x, acc[4*q+2]);
    acc[4*q+3] = fmaf(r.w, x, acc[4*q+3]);
  }
}

// acc[o] = binit + sum_t M[t][o] * bit_t   (binary input held as 3 words)
__device__ __forceinline__ void conv_bits72(float (&acc)[NC], const float* __restrict__ Ms,
                                            unsigned w0, unsigned w1, unsigned w2, float binit)
{
#pragma unroll
  for (int o = 0; o < NC; ++o) acc[o] = binit;
  const float* p = Ms;
#pragma unroll 1
  for (int j = 0; j < 32; ++j, p += NC) {
    float x = (float)((w0 >> j) & 1u);
    fma_row72(acc, p, x);
  }
#pragma unroll 1
  for (int j = 0; j < 32; ++j, p += NC) {
    float x = (float)((w1 >> j) & 1u);
    fma_row72(acc, p, x);
  }
#pragma unroll 1
  for (int j = 0; j < 8; ++j, p += NC) {   // only low 8 bits of w2 valid
    float x = (float)((w2 >> j) & 1u);
    fma_row72(acc, p, x);
  }
}

// build 72x72 conv-as-matvec matrix MT[t*72+o] from 13x13 kernel
__device__ __forceinline__ void stage_convmat(float* dst, const float* __restrict__ w, int tid)
{
  for (int r = tid; r < 5184; r += NT) {
    int t = r / NC, o = r - t * NC;
    int hi = t / 6, wi = t - 6 * hi;
    int ho = o / 6, wo = o - 6 * ho;
    int dr = hi - ho + 6, dc = wi - wo + 6;
    dst[r] = (dr >= 0 && dr < 13) ? w[dr * 13 + dc] : 0.f;
  }
}

__global__ __launch_bounds__(NT, 1) void fused_all(
    const int* __restrict__ dots,
    const float* __restrict__ w_each, const float* __restrict__ b_each,
    const float* __restrict__ w_not,  const float* __restrict__ b_not,
    const float* __restrict__ w_not2, const float* __restrict__ b_not2,
    const float* __restrict__ w_empty,const float* __restrict__ b_empty,
    const float* __restrict__ W1, const float* __restrict__ b1,
    const float* __restrict__ W2, const float* __restrict__ b2,
    const float* __restrict__ W3, const float* __restrict__ b3,
    float* __restrict__ out)
{
  __shared__ float sB[15552];
  const int tid = threadIdx.x;
  const int b = blockIdx.x * NT + tid;

  // ---- stage conv matrices (each/not/empty) while building masks ----
  stage_convmat(sB + 0,     w_each,  tid);
  stage_convmat(sB + 5184,  w_not,   tid);
  stage_convmat(sB + 10368, w_empty, tid);

  // per-lane kind bitmasks: mkw[k][word], k=0 empty-mask, 1..4 kinds
  unsigned mkw[5][3] = {};
#pragma unroll
  for (int c = 0; c < NC; ++c) {
    int v = dots[c * BN + b];
#pragma unroll
    for (int k = 0; k < 5; ++k)
      mkw[k][c >> 5] |= (unsigned)(v == k) << (c & 31);
  }

  float S[NC], acc[NC], acv[NC];
  __syncthreads();

  // ---- phase A: empty conv -> S ----
  conv_bits72(S, sB + 10368, mkw[0][0], mkw[0][1], mkw[0][2], *b_empty);

  // z bits per kind: (mask_k + empty) > 0
  unsigned zw[4][3];
#pragma unroll
  for (int k = 0; k < 4; ++k) {
    unsigned z0 = 0, z1 = 0, z2 = 0;
#pragma unroll
    for (int t = 0; t < NC; ++t) {
      unsigned mb = (mkw[k + 1][t >> 5] >> (t & 31)) & 1u;
      unsigned zb = (S[t] + (float)mb) > 0.f ? 1u : 0u;
      if (t < 32) z0 |= zb << t;
      else if (t < 64) z1 |= zb << (t - 32);
      else z2 |= zb << (t - 64);
    }
    zw[k][0] = z0; zw[k][1] = z1; zw[k][2] = z2;
  }

  // each-convs: S += ecv_k at kind-k cells
  {
    float bea = *b_each;
#pragma unroll
    for (int k = 1; k <= 4; ++k) {
      conv_bits72(acc, sB + 0, mkw[k][0], mkw[k][1], mkw[k][2], bea);
#pragma unroll
      for (int t = 0; t < NC; ++t)
        if ((mkw[k][t >> 5] >> (t & 31)) & 1u) S[t] += acc[t];
    }
  }
  // S is now CLEAN (ecv_sel + empty) and must stay clean for phase C.

  // acv2 init: 0 at empty cells, else S (not-conv subtracted next)
#pragma unroll
  for (int t = 0; t < NC; ++t)
    acv[t] = ((mkw[0][t >> 5] >> (t & 31)) & 1u) ? 0.f : S[t];

  // ---- phase B: not-convs (input ~z); acv -= not_conv at kind cells ----
  {
    float bno = *b_not;
#pragma unroll
    for (int k = 0; k < 4; ++k) {
      conv_bits72(acc, sB + 5184, ~zw[k][0], ~zw[k][1], ~zw[k][2], bno);
#pragma unroll
      for (int t = 0; t < NC; ++t)
        if ((mkw[k + 1][t >> 5] >> (t & 31)) & 1u) acv[t] -= acc[t];
    }
  }

  // ---- restage: acv columns + not2 matrix ----
  __syncthreads();
  stage_convmat(sB + 9216, w_not2, tid);
#pragma unroll
  for (int t = 0; t < NC; ++t) sB[t * NT + tid] = acv[t];
  __syncthreads();

  // ---- phase C: 4 sequential not2 convs (uses CLEAN S in merge) ----
  {
    float bn2 = *b_not2;
#pragma unroll
    for (int k = 0; k < 4; ++k) {
#pragma unroll
      for (int o = 0; o < NC; ++o) acc[o] = bn2;
      const float* p = sB + 9216;
#pragma unroll 1
      for (int j = 0; j < 32; ++j, p += NC) {
        float a = sB[j * NT + tid];
        float x = ((zw[k][0] >> j) & 1u) ? 0.f : a;
        fma_row72(acc, p, x);
      }
#pragma unroll 1
      for (int j = 0; j < 32; ++j, p += NC) {
        float a = sB[(32 + j) * NT + tid];
        float x = ((zw[k][1] >> j) & 1u) ? 0.f : a;
        fma_row72(acc, p, x);
      }
#pragma unroll 1
      for (int j = 0; j < 8; ++j, p += NC) {
        float a = sB[(64 + j) * NT + tid];
        float x = ((zw[k][2] >> j) & 1u) ? 0.f : a;
        fma_row72(acc, p, x);
      }
      // merge at kind cells + write-through to LDS column (column is lane-private)
#pragma unroll
      for (int t = 0; t < NC; ++t)
        if ((mkw[k + 1][t >> 5] >> (t & 31)) & 1u) {
          acv[t] += S[t] + acc[t];
          sB[t * NT + tid] = acv[t];
        }
    }
  }

  // ---- FC1: 72 -> 100, W1T staged in two halves ----
  float h[100];
#pragma unroll
  for (int o = 0; o < 100; ++o) h[o] = b1[o];
#pragma unroll 1
  for (int half = 0; half < 2; ++half) {
    __syncthreads();                     // all waves done with not2 / previous half
    for (int j = tid; j < 3600; j += NT) {
      int t = j / 100, o = j - 100 * t;
      sB[9216 + j] = W1[o * NC + (half * 36 + t)];
    }
    __syncthreads();
#pragma unroll 1
    for (int tt = 0; tt < 36; ++tt) {
      float x = sB[(half * 36 + tt) * NT + tid];   // acvL column read
      const float* r = sB + 9216 + tt * 100;
#pragma unroll
      for (int q = 0; q < 25; ++q) {
        float4 v4 = ((const float4*)r)[q];
        h[4*q+0] = fmaf(v4.x, x, h[4*q+0]);
        h[4*q+1] = fmaf(v4.y, x, h[4*q+1]);
        h[4*q+2] = fmaf(v4.z, x, h[4*q+2]);
        h[4*q+3] = fmaf(v4.w, x, h[4*q+3]);
      }
    }
  }
#pragma unroll
  for (int o = 0; o < 100; ++o) h[o] = fmaxf(h[o], 0.2f * h[o]);  // leaky relu

  // ---- FC2: 100 -> 100, h1 in LDS columns, W2T in 4 chunks ----
  __syncthreads();                       // all waves done reading acvL/W1T
#pragma unroll
  for (int o = 0; o < 100; ++o) sB[o * NT + tid] = h[o];
  float g[100];
#pragma unroll
  for (int o = 0; o < 100; ++o) g[o] = b2[o];
#pragma unroll 1
  for (int ch = 0; ch < 4; ++ch) {
    __syncthreads();
    for (int j = tid; j < 2500; j += NT) {
      int t = j / 100, o = j - 100 * t;
      sB[12800 + j] = W2[o * 100 + (ch * 25 + t)];
    }
    __syncthreads();
#pragma unroll 1
    for (int tt = 0; tt < 25; ++tt) {
      float x = sB[(ch * 25 + tt) * NT + tid];
      const float* r = sB + 12800 + tt * 100;
#pragma unroll
      for (int q = 0; q < 25; ++q) {
        float4 v4 = ((const float4*)r)[q];
        g[4*q+0] = fmaf(v4.x, x, g[4*q+0]);
        g[4*q+1] = fmaf(v4.y, x, g[4*q+1]);
        g[4*q+2] = fmaf(v4.z, x, g[4*q+2]);
        g[4*q+3] = fmaf(v4.w, x, g[4*q+3]);
      }
    }
  }

  // ---- FC3: leaky + dot with W3 ----
  float o0 = *b3;
#pragma unroll
  for (int j = 0; j < 100; ++j) {
    float v = fmaxf(g[j], 0.2f * g[j]);
    o0 = fmaf(W3[j], v, o0);
  }
  out[b] = o0;
}

extern "C" void kernel_launch(void* const* d_in, const int* in_sizes, int n_in,
                              void* d_out, int out_size, void* d_ws, size_t ws_size,
                              hipStream_t stream)
{
  const int*   dots    = (const int*)d_in[0];
  const float* w_each  = (const float*)d_in[1];
  const float* b_each  = (const float*)d_in[2];
  const float* w_not   = (const float*)d_in[3];
  const float* b_not   = (const float*)d_in[4];
  const float* w_not2  = (const float*)d_in[5];
  const float* b_not2  = (const float*)d_in[6];
  const float* w_empty = (const float*)d_in[7];
  const float* b_empty = (const float*)d_in[8];
  const float* W1 = (const float*)d_in[9];
  const float* b1 = (const float*)d_in[10];
  const float* W2 = (const float*)d_in[11];
  const float* b2 = (const float*)d_in[12];
  const float* W3 = (const float*)d_in[13];
  const float* b3 = (const float*)d_in[14];

  (void)in_sizes; (void)n_in; (void)out_size; (void)d_ws; (void)ws_size;

  fused_all<<<NBLK, NT, 0, stream>>>(
      dots, w_each, b_each, w_not, b_not, w_not2, b_not2, w_empty, b_empty,
      W1, b1, W2, b2, W3, b3, (float*)d_out);
}

// Round 6
// 558.932 us; speedup vs baseline: 1.7392x; 1.0724x over previous
//
#include <hip/hip_runtime.h>

#define BN 65536
#define NT 256
#define NB 128            // batch elements per block (2 threads each)
#define NBLK (BN / NB)    // 512 blocks -> 2 blocks/CU (62 KB LDS), 2 waves/SIMD
#define NC 72
#define HC 36             // outputs per thread (half of 72)

// LDS: 15552 floats = 62208 B
//  phase A/B : each-mat @0, not-mat @5184, empty-mat @10368   (each 5184)
//  z-exchange: zx u32 [4][4][128] @10368 (overlays empty-mat after phase A)
//  phase C   : acv cols [72][128] @0 (9216), not2-mat @10368 (5184)
//  FC1       : acv cols @0, W1T chunk (36x100) @10368 (3600)
//  FC2       : h cols [100][128] @0 (12800), W2T chunk (25x100) @12800 (2500)
//  FC3       : ps[128] @15300

__device__ __forceinline__ void fma_half(float (&acc)[HC], const float* p, float x)
{
#pragma unroll
  for (int q = 0; q < 9; ++q) {
    float4 r = ((const float4*)p)[q];
    acc[4*q+0] = fmaf(r.x, x, acc[4*q+0]);
    acc[4*q+1] = fmaf(r.y, x, acc[4*q+1]);
    acc[4*q+2] = fmaf(r.z, x, acc[4*q+2]);
    acc[4*q+3] = fmaf(r.w, x, acc[4*q+3]);
  }
}

// acc[o] = binit + sum_t M[t][obase+o] * bit_t  over all 72 t
__device__ __forceinline__ void conv_bits_half(float (&acc)[HC], const float* __restrict__ Ms,
                                               int obase, unsigned w0, unsigned w1, unsigned w2,
                                               float binit)
{
#pragma unroll
  for (int o = 0; o < HC; ++o) acc[o] = binit;
  const float* p = Ms + obase;
#pragma unroll 1
  for (int j = 0; j < 32; ++j, p += NC) fma_half(acc, p, (float)((w0 >> j) & 1u));
#pragma unroll 1
  for (int j = 0; j < 32; ++j, p += NC) fma_half(acc, p, (float)((w1 >> j) & 1u));
#pragma unroll 1
  for (int j = 0; j < 8; ++j, p += NC)  fma_half(acc, p, (float)((w2 >> j) & 1u));
}

// 72x72 conv-as-matvec matrix MT[t*72+o] from 13x13 kernel
__device__ __forceinline__ void stage_convmat(float* dst, const float* __restrict__ w, int tid)
{
  for (int r = tid; r < 5184; r += NT) {
    int t = r / NC, o = r - t * NC;
    int hi = t / 6, wi = t - 6 * hi;
    int ho = o / 6, wo = o - 6 * ho;
    int dr = hi - ho + 6, dc = wi - wo + 6;
    dst[r] = (dr >= 0 && dr < 13) ? w[dr * 13 + dc] : 0.f;
  }
}

__global__ __launch_bounds__(NT, 2) void fused_all(
    const int* __restrict__ dots,
    const float* __restrict__ w_each, const float* __restrict__ b_each,
    const float* __restrict__ w_not,  const float* __restrict__ b_not,
    const float* __restrict__ w_not2, const float* __restrict__ b_not2,
    const float* __restrict__ w_empty,const float* __restrict__ b_empty,
    const float* __restrict__ W1, const float* __restrict__ b1,
    const float* __restrict__ W2, const float* __restrict__ b2,
    const float* __restrict__ W3, const float* __restrict__ b3,
    float* __restrict__ out)
{
  __shared__ float sB[15552];
  const int tid   = threadIdx.x;
  const int bidx  = tid & (NB - 1);
  const int half  = tid >> 7;         // 0: outputs [0,36), 1: [36,72)
  const int obase = half * HC;
  const int b     = blockIdx.x * NB + bidx;

  stage_convmat(sB + 0,     w_each,  tid);
  stage_convmat(sB + 5184,  w_not,   tid);
  stage_convmat(sB + 10368, w_empty, tid);

  // full kind bitmasks per thread (both halves need all 72 bits as conv inputs)
  unsigned mkw[5][3] = {};
#pragma unroll
  for (int c = 0; c < NC; ++c) {
    int v = dots[c * BN + b];
#pragma unroll
    for (int k = 0; k < 5; ++k)
      mkw[k][c >> 5] |= (unsigned)(v == k) << (c & 31);
  }

  float S[HC], acc[HC], acv[HC];
  __syncthreads();

  // ---- phase A: empty conv -> S (own half) ----
  conv_bits_half(S, sB + 10368, obase, mkw[0][0], mkw[0][1], mkw[0][2], *b_empty);
  __syncthreads();                       // all empty-mat reads done (zx overlays it)

  // z partial words for own cells: zbit_t = (S + mask_{k+1}) > 0
  {
    unsigned* zxu = (unsigned*)(sB + 10368);
#pragma unroll
    for (int k = 0; k < 4; ++k) {
      unsigned za = 0, zb = 0;
#pragma unroll
      for (int i = 0; i < HC; ++i) {
        int t = obase + i;
        unsigned mw = t < 32 ? mkw[k+1][0] : (t < 64 ? mkw[k+1][1] : mkw[k+1][2]);
        unsigned mb = (mw >> (t & 31)) & 1u;
        unsigned zbit = (S[i] + (float)mb) > 0.f ? 1u : 0u;
        if (half == 0) { if (i < 32) za |= zbit << i;       else zb |= zbit << (i - 32); }
        else           { if (i < 28) za |= zbit << (i + 4); else zb |= zbit << (i - 28); }
      }
      zxu[(k * 4 + half * 2 + 0) * NB + bidx] = za;
      zxu[(k * 4 + half * 2 + 1) * NB + bidx] = zb;
    }
  }

  // each-convs: S += ecv_k at kind-k cells (own half)
  {
    float bea = *b_each;
#pragma unroll
    for (int k = 1; k <= 4; ++k) {
      conv_bits_half(acc, sB + 0, obase, mkw[k][0], mkw[k][1], mkw[k][2], bea);
#pragma unroll
      for (int i = 0; i < HC; ++i) {
        int t = obase + i;
        unsigned mw = t < 32 ? mkw[k][0] : (t < 64 ? mkw[k][1] : mkw[k][2]);
        if ((mw >> (t & 31)) & 1u) S[i] += acc[i];
      }
    }
  }
  // S is CLEAN (empty + ecv_sel); stays clean for phase C merge.

  // acv init: 0 at empty cells
#pragma unroll
  for (int i = 0; i < HC; ++i) {
    int t = obase + i;
    unsigned ew = t < 32 ? mkw[0][0] : (t < 64 ? mkw[0][1] : mkw[0][2]);
    acv[i] = ((ew >> (t & 31)) & 1u) ? 0.f : S[i];
  }

  __syncthreads();                       // zx complete
  unsigned zw[4][3];
  {
    const unsigned* zxu = (const unsigned*)(sB + 10368);
#pragma unroll
    for (int k = 0; k < 4; ++k) {
      zw[k][0] = zxu[(k * 4 + 0) * NB + bidx];
      zw[k][1] = zxu[(k * 4 + 1) * NB + bidx] | zxu[(k * 4 + 2) * NB + bidx];
      zw[k][2] = zxu[(k * 4 + 3) * NB + bidx];
    }
  }

  // ---- phase B: not-convs (input ~z); acv -= not_conv at kind cells ----
  {
    float bno = *b_not;
#pragma unroll
    for (int k = 0; k < 4; ++k) {
      conv_bits_half(acc, sB + 5184, obase, ~zw[k][0], ~zw[k][1], ~zw[k][2], bno);
#pragma unroll
      for (int i = 0; i < HC; ++i) {
        int t = obase + i;
        unsigned mw = t < 32 ? mkw[k+1][0] : (t < 64 ? mkw[k+1][1] : mkw[k+1][2]);
        if ((mw >> (t & 31)) & 1u) acv[i] -= acc[i];
      }
    }
  }

  __syncthreads();                       // done with each/not mats
  // acv columns + not2 matrix
#pragma unroll
  for (int i = 0; i < HC; ++i) sB[(obase + i) * NB + bidx] = acv[i];
  stage_convmat(sB + 10368, w_not2, tid);
  __syncthreads();

  // ---- phase C: 4 sequential not2 convs ----
  {
    float bn2 = *b_not2;
#pragma unroll
    for (int k = 0; k < 4; ++k) {
#pragma unroll
      for (int o = 0; o < HC; ++o) acc[o] = bn2;
      const float* p = sB + 10368 + obase;
      unsigned z0 = zw[k][0], z1 = zw[k][1], z2 = zw[k][2];
#pragma unroll 1
      for (int j = 0; j < 32; ++j, p += NC) {
        float a = sB[j * NB + bidx];
        fma_half(acc, p, ((z0 >> j) & 1u) ? 0.f : a);
      }
#pragma unroll 1
      for (int j = 0; j < 32; ++j, p += NC) {
        float a = sB[(32 + j) * NB + bidx];
        fma_half(acc, p, ((z1 >> j) & 1u) ? 0.f : a);
      }
#pragma unroll 1
      for (int j = 0; j < 8; ++j, p += NC) {
        float a = sB[(64 + j) * NB + bidx];
        fma_half(acc, p, ((z2 >> j) & 1u) ? 0.f : a);
      }
      __syncthreads();                   // all conv reads done before merge writes
#pragma unroll
      for (int i = 0; i < HC; ++i) {
        int t = obase + i;
        unsigned mw = t < 32 ? mkw[k+1][0] : (t < 64 ? mkw[k+1][1] : mkw[k+1][2]);
        if ((mw >> (t & 31)) & 1u) {
          acv[i] += S[i] + acc[i];
          sB[t * NB + bidx] = acv[i];
        }
      }
      __syncthreads();                   // merge visible before next conv / FC1
    }
  }

  // ---- FC1: 72 -> 100 (own 50 outputs), W1T in 2 chunks of 36 rows ----
  float h[50];
#pragma unroll
  for (int o = 0; o < 50; ++o) h[o] = b1[half * 50 + o];
#pragma unroll 1
  for (int ch = 0; ch < 2; ++ch) {
    const int cb = ch * 36;
    for (int j = tid; j < 3600; j += NT) {
      int tr = j / 100, o = j - 100 * tr;
      sB[10368 + j] = W1[o * NC + cb + tr];
    }
    __syncthreads();
#pragma unroll 1
    for (int tt = 0; tt < 36; ++tt) {
      float x = sB[(cb + tt) * NB + bidx];
      const float* r = sB + 10368 + tt * 100 + half * 50;
#pragma unroll
      for (int q = 0; q < 12; ++q) {
        float4 v4 = ((const float4*)r)[q];
        h[4*q+0] = fmaf(v4.x, x, h[4*q+0]);
        h[4*q+1] = fmaf(v4.y, x, h[4*q+1]);
        h[4*q+2] = fmaf(v4.z, x, h[4*q+2]);
        h[4*q+3] = fmaf(v4.w, x, h[4*q+3]);
      }
      h[48] = fmaf(r[48], x, h[48]);
      h[49] = fmaf(r[49], x, h[49]);
    }
    __syncthreads();                     // chunk reads done before restage/reuse
  }
#pragma unroll
  for (int o = 0; o < 50; ++o) h[o] = fmaxf(h[o], 0.2f * h[o]);   // leaky 0.2

  // ---- FC2: 100 -> 100 (own 50), h cols in LDS, W2T in 4 chunks of 25 rows ----
#pragma unroll
  for (int o = 0; o < 50; ++o) sB[(half * 50 + o) * NB + bidx] = h[o];
  float g[50];
#pragma unroll
  for (int o = 0; o < 50; ++o) g[o] = b2[half * 50 + o];
#pragma unroll 1
  for (int ch = 0; ch < 4; ++ch) {
    const int cb = ch * 25;
    for (int j = tid; j < 2500; j += NT) {
      int tr = j / 100, o = j - 100 * tr;
      sB[12800 + j] = W2[o * 100 + cb + tr];
    }
    __syncthreads();                     // h cols (ch0) + chunk staged
#pragma unroll 1
    for (int tt = 0; tt < 25; ++tt) {
      float x = sB[(cb + tt) * NB + bidx];
      const float* r = sB + 12800 + tt * 100 + half * 50;
#pragma unroll
      for (int q = 0; q < 12; ++q) {
        float4 v4 = ((const float4*)r)[q];
        g[4*q+0] = fmaf(v4.x, x, g[4*q+0]);
        g[4*q+1] = fmaf(v4.y, x, g[4*q+1]);
        g[4*q+2] = fmaf(v4.z, x, g[4*q+2]);
        g[4*q+3] = fmaf(v4.w, x, g[4*q+3]);
      }
      g[48] = fmaf(r[48], x, g[48]);
      g[49] = fmaf(r[49], x, g[49]);
    }
    __syncthreads();                     // chunk reads done before restage
  }

  // ---- FC3: leaky + partial dot, combine halves ----
  float pd = 0.f;
#pragma unroll
  for (int j = 0; j < 50; ++j) {
    float v = fmaxf(g[j], 0.2f * g[j]);
    pd = fmaf(W3[half * 50 + j], v, pd);
  }
  if (half == 1) sB[15300 + bidx] = pd;
  __syncthreads();
  if (half == 0) out[b] = pd + sB[15300 + bidx] + *b3;
}

extern "C" void kernel_launch(void* const* d_in, const int* in_sizes, int n_in,
                              void* d_out, int out_size, void* d_ws, size_t ws_size,
                              hipStream_t stream)
{
  const int*   dots    = (const int*)d_in[0];
  const float* w_each  = (const float*)d_in[1];
  const float* b_each  = (const float*)d_in[2];
  const float* w_not   = (const float*)d_in[3];
  const float* b_not   = (const float*)d_in[4];
  const float* w_not2  = (const float*)d_in[5];
  const float* b_not2  = (const float*)d_in[6];
  const float* w_empty = (const float*)d_in[7];
  const float* b_empty = (const float*)d_in[8];
  const float* W1 = (const float*)d_in[9];
  const float* b1 = (const float*)d_in[10];
  const float* W2 = (const float*)d_in[11];
  const float* b2 = (const float*)d_in[12];
  const float* W3 = (const float*)d_in[13];
  const float* b3 = (const float*)d_in[14];

  (void)in_sizes; (void)n_in; (void)out_size; (void)d_ws; (void)ws_size;

  fused_all<<<NBLK, NT, 0, stream>>>(
      dots, w_each, b_each, w_not, b_not, w_not2, b_not2, w_empty, b_empty,
      W1, b1, W2, b2, W3, b3, (float*)d_out);
}

// Round 7
// 71.803 us; speedup vs baseline: 13.5383x; 7.7842x over previous
//
#include <hip/hip_runtime.h>

#define BN 65536
#define NT 256
#define NBB 64            // batches per block (wave w owns batches w*16..w*16+15)
#define NBLK (BN / NBB)   // 1024 blocks

typedef unsigned int uint;
typedef unsigned short ushort;
typedef __attribute__((ext_vector_type(8))) short bf16x8;
typedef __attribute__((ext_vector_type(4))) float f32x4;

// LDS layout (u32 units), total 15504 u32 = 62016 B
#define L_AF 0        // 6400: staged A-frag table (max chunk)
#define L_XV 6400     // 6528: packed X (bf16 dup) [64][100] + 128 tail pad
#define L_Z  12928    // 1280: z bytes [64][80]
#define L_MK 14208    // 960 : mask words [5 kind][3 word][64 batch]
#define L_B1 15168    // 112 f32 (pad 0)
#define L_B2 15280    // 112
#define L_W3 15392    // 112
#define L_TOT 15504

// ws (u16 units): conv mats m*12800 (each=0,not=1,not2=2,empty=3), W1@51200 (7ti x 5ks), W2@69120 (7ti x 7ks)
#define WS_W1 51200
#define WS_W2 69120
#define WS_TOT 94208

__device__ __forceinline__ uint f2b(float f){           // bf16 rne bits
  uint u = __float_as_uint(f);
  return (u + 0x7FFFu + ((u >> 16) & 1u)) >> 16;
}
__device__ __forceinline__ float b2f(uint h){ return __uint_as_float(h << 16); }
__device__ __forceinline__ uint packdup(float f){ uint b = f2b(f); return b | (b << 16); }

union BU { uint u[4]; bf16x8 v; };

// ---------------- setup: build all MFMA A-fragment tables (hi/lo K-interleaved) ----------------
__global__ __launch_bounds__(256) void k_setup(
    const float* __restrict__ w_each, const float* __restrict__ w_not,
    const float* __restrict__ w_not2, const float* __restrict__ w_empty,
    const float* __restrict__ W1, const float* __restrict__ W2,
    ushort* __restrict__ wsp)
{
  int id = blockIdx.x * 256 + threadIdx.x;
  if (id >= WS_TOT) return;
  float val = 0.f;
  int part;
  if (id < 51200) {                       // conv mats
    int m = id / 12800, r = id % 12800;
    int fi = r >> 3, j = r & 7;
    int l = fi & 63, tk = fi >> 6;
    int ks = tk % 5, ti = tk / 5;
    int row = ti * 16 + (l & 15);         // output cell
    int k = ks * 32 + (l >> 4) * 8 + j;
    int t = k >> 1; part = k & 1;         // input cell, hi/lo slot
    if (row < 72 && t < 72) {
      int dr = t / 6 - row / 6 + 6, dc = t % 6 - row % 6 + 6;
      const float* w = m == 0 ? w_each : m == 1 ? w_not : m == 2 ? w_not2 : w_empty;
      if (dr >= 0 && dr < 13) val = w[dr * 13 + dc];
    }
  } else if (id < WS_W2) {                // W1
    int r = id - WS_W1;
    int fi = r >> 3, j = r & 7;
    int l = fi & 63, tk = fi >> 6;
    int ks = tk % 5, ti = tk / 5;
    int row = ti * 16 + (l & 15);
    int k = ks * 32 + (l >> 4) * 8 + j;
    int t = k >> 1; part = k & 1;
    if (row < 100 && t < 72) val = W1[row * 72 + t];
  } else {                                // W2
    int r = id - WS_W2;
    int fi = r >> 3, j = r & 7;
    int l = fi & 63, tk = fi >> 6;
    int ks = tk % 7, ti = tk / 7;
    int row = ti * 16 + (l & 15);
    int k = ks * 32 + (l >> 4) * 8 + j;
    int t = k >> 1; part = k & 1;
    if (row < 100 && t < 100) val = W2[row * 100 + t];
  }
  uint h = f2b(val);
  if (part) { float rem = val - b2f(h); h = f2b(rem); }
  wsp[id] = (ushort)h;
}

// stage frags (all ti, ks in [ks0,ks0+nks)) from a table of width KW into L_AF
__device__ __forceinline__ void stageChunk(uint* sB, const ushort* wsp, int baseU16,
                                           int NTI, int KW, int ks0, int nks, int tid)
{
  const int tot = NTI * nks * 64;
  const uint4* src = (const uint4*)(wsp + baseU16);
  uint4* dst = (uint4*)(sB + L_AF);
  for (int i = tid; i < tot; i += NT) {
    int l = i & 63, tk = i >> 6;
    int ksl = tk % nks, ti = tk / nks;
    dst[(ti * nks + ksl) * 64 + l] = src[(ti * KW + ks0 + ksl) * 64 + l];
  }
}

__global__ __launch_bounds__(NT, 2) void k_main(
    const int* __restrict__ dots, const ushort* __restrict__ wsp,
    const float* __restrict__ b_each, const float* __restrict__ b_not,
    const float* __restrict__ b_not2, const float* __restrict__ b_empty,
    const float* __restrict__ b1, const float* __restrict__ b2,
    const float* __restrict__ W3, const float* __restrict__ b3,
    float* __restrict__ out)
{
  __shared__ uint sB[L_TOT];
  const int tid = threadIdx.x;
  const int wid = tid >> 6, lane = tid & 63;
  const int grp = lane >> 4, col = lane & 15;
  const int bl = wid * 16 + col;          // local batch this lane's B/D columns belong to

  const float c_each = *b_each, c_not = *b_not, c_not2 = *b_not2, c_empty = *b_empty;
  const float c_b3 = *b3;

  // ---- prologue: zero XV (NaN-safety for padded reads), stage biases/W3 + empty mat, build masks ----
  for (int i = tid; i < 6528; i += NT) sB[L_XV + i] = 0;
  for (int i = tid; i < 112; i += NT) {
    ((float*)(sB + L_B1))[i] = (i < 100) ? b1[i] : 0.f;
    ((float*)(sB + L_B2))[i] = (i < 100) ? b2[i] : 0.f;
    ((float*)(sB + L_W3))[i] = (i < 100) ? W3[i] : 0.f;
  }
  stageChunk(sB, wsp, 3 * 12800, 5, 5, 0, 5, tid);   // empty matrix
  if (lane < 16) {
    const int bb = wid * 16 + lane;
    const int gb = blockIdx.x * NBB + bb;
    uint mk[5][3] = {};
#pragma unroll
    for (int c = 0; c < 72; ++c) {
      int v = dots[c * BN + gb];
#pragma unroll
      for (int k = 0; k < 5; ++k)
        mk[k][c >> 5] |= (uint)(v == k) << (c & 31);
    }
#pragma unroll
    for (int k = 0; k < 5; ++k)
#pragma unroll
      for (int w = 0; w < 3; ++w)
        sB[L_MK + (k * 3 + w) * 64 + bb] = mk[k][w];
  }
  __syncthreads();

  f32x4 S5[5], A5[5], D5[5];
  BU Bv[5];
  uint ew0, ew1, ew2;

  // ---- empty conv -> S ----
  {
    ew0 = sB[L_MK + 0 * 64 + bl]; ew1 = sB[L_MK + 1 * 64 + bl]; ew2 = sB[L_MK + 2 * 64 + bl];
#pragma unroll
    for (int ks = 0; ks < 5; ++ks) {
      uint wv = (ks >> 1) == 0 ? ew0 : (ks >> 1) == 1 ? ew1 : ew2;
      int tb = ks * 16 + grp * 4;
#pragma unroll
      for (int q = 0; q < 4; ++q)
        Bv[ks].u[q] = ((wv >> ((tb + q) & 31)) & 1u) ? 0x3F803F80u : 0u;
    }
    const bf16x8* AF = (const bf16x8*)sB;
#pragma unroll
    for (int ti = 0; ti < 5; ++ti) {
      f32x4 d = {c_empty, c_empty, c_empty, c_empty};
#pragma unroll
      for (int ks = 0; ks < 5; ++ks)
        d = __builtin_amdgcn_mfma_f32_16x16x32_bf16(AF[(ti * 5 + ks) * 64 + lane], Bv[ks].v, d, 0, 0, 0);
      S5[ti] = d;
    }
  }

  // ---- z bytes: bit(k-1) = (empty + mask_k) > 0, packed per cell ----
  {
    uint zws[5] = {0, 0, 0, 0, 0};
#pragma unroll
    for (int k = 1; k <= 4; ++k) {
      uint a0 = sB[L_MK + (k * 3 + 0) * 64 + bl];
      uint a1 = sB[L_MK + (k * 3 + 1) * 64 + bl];
      uint a2 = sB[L_MK + (k * 3 + 2) * 64 + bl];
#pragma unroll
      for (int ti = 0; ti < 5; ++ti) {
        uint wv = (ti >> 1) == 0 ? a0 : (ti >> 1) == 1 ? a1 : a2;
        int cb = ti * 16 + grp * 4;
#pragma unroll
        for (int r = 0; r < 4; ++r) {
          float mb = (float)((wv >> ((cb + r) & 31)) & 1u);
          if (S5[ti][r] + mb > 0.f) zws[ti] |= 1u << (r * 8 + (k - 1));
        }
      }
    }
#pragma unroll
    for (int ti = 0; ti < 5; ++ti)
      sB[L_Z + bl * 20 + ti * 4 + grp] = zws[ti];
  }

  // ---- each convs: S += ecv_k at kind-k cells ----
  __syncthreads();
  stageChunk(sB, wsp, 0, 5, 5, 0, 5, tid);
  __syncthreads();
#pragma unroll 1
  for (int k = 1; k <= 4; ++k) {
    uint m0 = sB[L_MK + (k * 3 + 0) * 64 + bl];
    uint m1 = sB[L_MK + (k * 3 + 1) * 64 + bl];
    uint m2 = sB[L_MK + (k * 3 + 2) * 64 + bl];
#pragma unroll
    for (int ks = 0; ks < 5; ++ks) {
      uint wv = (ks >> 1) == 0 ? m0 : (ks >> 1) == 1 ? m1 : m2;
      int tb = ks * 16 + grp * 4;
#pragma unroll
      for (int q = 0; q < 4; ++q)
        Bv[ks].u[q] = ((wv >> ((tb + q) & 31)) & 1u) ? 0x3F803F80u : 0u;
    }
    const bf16x8* AF = (const bf16x8*)sB;
#pragma unroll
    for (int ti = 0; ti < 5; ++ti) {
      f32x4 d = {c_each, c_each, c_each, c_each};
#pragma unroll
      for (int ks = 0; ks < 5; ++ks)
        d = __builtin_amdgcn_mfma_f32_16x16x32_bf16(AF[(ti * 5 + ks) * 64 + lane], Bv[ks].v, d, 0, 0, 0);
      D5[ti] = d;
    }
#pragma unroll
    for (int ti = 0; ti < 5; ++ti) {
      uint wv = (ti >> 1) == 0 ? m0 : (ti >> 1) == 1 ? m1 : m2;
      int cb = ti * 16 + grp * 4;
#pragma unroll
      for (int r = 0; r < 4; ++r)
        if ((wv >> ((cb + r) & 31)) & 1u) S5[ti][r] += D5[ti][r];
    }
  }

  // ---- acv init: 0 at empty cells, else clean S ----
#pragma unroll
  for (int ti = 0; ti < 5; ++ti) {
    uint wv = (ti >> 1) == 0 ? ew0 : (ti >> 1) == 1 ? ew1 : ew2;
    int cb = ti * 16 + grp * 4;
#pragma unroll
    for (int r = 0; r < 4; ++r)
      A5[ti][r] = ((wv >> ((cb + r) & 31)) & 1u) ? 0.f : S5[ti][r];
  }

  // ---- not convs: acv -= not_conv at kind cells (input = ~z) ----
  __syncthreads();
  stageChunk(sB, wsp, 1 * 12800, 5, 5, 0, 5, tid);
  __syncthreads();
#pragma unroll 1
  for (int k = 1; k <= 4; ++k) {
#pragma unroll
    for (int ks = 0; ks < 5; ++ks) {
      uint zw = sB[L_Z + bl * 20 + ks * 4 + grp];
#pragma unroll
      for (int q = 0; q < 4; ++q)
        Bv[ks].u[q] = ((zw >> (q * 8 + (k - 1))) & 1u) ? 0u : 0x3F803F80u;
    }
    const bf16x8* AF = (const bf16x8*)sB;
#pragma unroll
    for (int ti = 0; ti < 5; ++ti) {
      f32x4 d = {c_not, c_not, c_not, c_not};
#pragma unroll
      for (int ks = 0; ks < 5; ++ks)
        d = __builtin_amdgcn_mfma_f32_16x16x32_bf16(AF[(ti * 5 + ks) * 64 + lane], Bv[ks].v, d, 0, 0, 0);
      D5[ti] = d;
    }
    uint m0 = sB[L_MK + (k * 3 + 0) * 64 + bl];
    uint m1 = sB[L_MK + (k * 3 + 1) * 64 + bl];
    uint m2 = sB[L_MK + (k * 3 + 2) * 64 + bl];
#pragma unroll
    for (int ti = 0; ti < 5; ++ti) {
      uint wv = (ti >> 1) == 0 ? m0 : (ti >> 1) == 1 ? m1 : m2;
      int cb = ti * 16 + grp * 4;
#pragma unroll
      for (int r = 0; r < 4; ++r)
        if ((wv >> ((cb + r) & 31)) & 1u) A5[ti][r] -= D5[ti][r];
    }
  }

  // ---- pack acv into XV (bf16 dup u32) ----
#pragma unroll
  for (int ti = 0; ti < 5; ++ti) {
    uint4 pk;
    pk.x = packdup(A5[ti][0]); pk.y = packdup(A5[ti][1]);
    pk.z = packdup(A5[ti][2]); pk.w = packdup(A5[ti][3]);
    ((uint4*)(sB + L_XV))[bl * 25 + ti * 4 + grp] = pk;
  }

  // ---- phase C: 4 sequential not2 convs (wave-private state, no barriers in loop) ----
  __syncthreads();
  stageChunk(sB, wsp, 2 * 12800, 5, 5, 0, 5, tid);
  __syncthreads();
#pragma unroll 1
  for (int k = 1; k <= 4; ++k) {
#pragma unroll
    for (int ks = 0; ks < 5; ++ks) {
      uint4 xv = ((const uint4*)(sB + L_XV))[bl * 25 + ks * 4 + grp];
      uint zw = sB[L_Z + bl * 20 + ks * 4 + grp];
      Bv[ks].u[0] = ((zw >> (0 * 8 + k - 1)) & 1u) ? 0u : xv.x;
      Bv[ks].u[1] = ((zw >> (1 * 8 + k - 1)) & 1u) ? 0u : xv.y;
      Bv[ks].u[2] = ((zw >> (2 * 8 + k - 1)) & 1u) ? 0u : xv.z;
      Bv[ks].u[3] = ((zw >> (3 * 8 + k - 1)) & 1u) ? 0u : xv.w;
    }
    const bf16x8* AF = (const bf16x8*)sB;
#pragma unroll
    for (int ti = 0; ti < 5; ++ti) {
      f32x4 d = {c_not2, c_not2, c_not2, c_not2};
#pragma unroll
      for (int ks = 0; ks < 5; ++ks)
        d = __builtin_amdgcn_mfma_f32_16x16x32_bf16(AF[(ti * 5 + ks) * 64 + lane], Bv[ks].v, d, 0, 0, 0);
      D5[ti] = d;
    }
    uint m0 = sB[L_MK + (k * 3 + 0) * 64 + bl];
    uint m1 = sB[L_MK + (k * 3 + 1) * 64 + bl];
    uint m2 = sB[L_MK + (k * 3 + 2) * 64 + bl];
#pragma unroll
    for (int ti = 0; ti < 5; ++ti) {
      uint wv = (ti >> 1) == 0 ? m0 : (ti >> 1) == 1 ? m1 : m2;
      int cb = ti * 16 + grp * 4;
#pragma unroll
      for (int r = 0; r < 4; ++r)
        if ((wv >> ((cb + r) & 31)) & 1u) A5[ti][r] += S5[ti][r] + D5[ti][r];
      uint4 pk;
      pk.x = packdup(A5[ti][0]); pk.y = packdup(A5[ti][1]);
      pk.z = packdup(A5[ti][2]); pk.w = packdup(A5[ti][3]);
      ((uint4*)(sB + L_XV))[bl * 25 + ti * 4 + grp] = pk;
    }
  }

  // ---- FC1: h = leaky(W1 x + b1), staged in 2 k-chunks ----
  BU Bx[5];
#pragma unroll
  for (int ks = 0; ks < 5; ++ks) {
    uint4 xv = ((const uint4*)(sB + L_XV))[bl * 25 + ks * 4 + grp];
    Bx[ks].u[0] = xv.x; Bx[ks].u[1] = xv.y; Bx[ks].u[2] = xv.z; Bx[ks].u[3] = xv.w;
  }
  f32x4 H[7];
#pragma unroll
  for (int ti = 0; ti < 7; ++ti) H[ti] = ((const f32x4*)(sB + L_B1))[ti * 4 + grp];
  __syncthreads();
  stageChunk(sB, wsp, WS_W1, 7, 5, 0, 3, tid);
  __syncthreads();
  {
    const bf16x8* AF = (const bf16x8*)sB;
#pragma unroll
    for (int ti = 0; ti < 7; ++ti)
#pragma unroll
      for (int ksl = 0; ksl < 3; ++ksl)
        H[ti] = __builtin_amdgcn_mfma_f32_16x16x32_bf16(AF[(ti * 3 + ksl) * 64 + lane], Bx[ksl].v, H[ti], 0, 0, 0);
  }
  __syncthreads();
  stageChunk(sB, wsp, WS_W1, 7, 5, 3, 2, tid);
  __syncthreads();
  {
    const bf16x8* AF = (const bf16x8*)sB;
#pragma unroll
    for (int ti = 0; ti < 7; ++ti)
#pragma unroll
      for (int ksl = 0; ksl < 2; ++ksl)
        H[ti] = __builtin_amdgcn_mfma_f32_16x16x32_bf16(AF[(ti * 2 + ksl) * 64 + lane], Bx[3 + ksl].v, H[ti], 0, 0, 0);
  }
#pragma unroll
  for (int ti = 0; ti < 7; ++ti) {
#pragma unroll
    for (int r = 0; r < 4; ++r) { float x = H[ti][r]; H[ti][r] = fmaxf(x, 0.2f * x); }
    if (ti < 6 || grp == 0) {              // rows >= 100 must not be stored
      uint4 pk;
      pk.x = packdup(H[ti][0]); pk.y = packdup(H[ti][1]);
      pk.z = packdup(H[ti][2]); pk.w = packdup(H[ti][3]);
      ((uint4*)(sB + L_XV))[bl * 25 + ti * 4 + grp] = pk;
    }
  }

  // ---- FC2: g = leaky(W2 h + b2), 3 k-chunks (3,2,2) ----
  BU By[7];
#pragma unroll
  for (int ks = 0; ks < 7; ++ks) {
    uint4 xv = ((const uint4*)(sB + L_XV))[bl * 25 + ks * 4 + grp];  // t>=100 killed by A zeros
    By[ks].u[0] = xv.x; By[ks].u[1] = xv.y; By[ks].u[2] = xv.z; By[ks].u[3] = xv.w;
  }
  f32x4 G[7];
#pragma unroll
  for (int ti = 0; ti < 7; ++ti) G[ti] = ((const f32x4*)(sB + L_B2))[ti * 4 + grp];
  __syncthreads();
  stageChunk(sB, wsp, WS_W2, 7, 7, 0, 3, tid);
  __syncthreads();
  {
    const bf16x8* AF = (const bf16x8*)sB;
#pragma unroll
    for (int ti = 0; ti < 7; ++ti)
#pragma unroll
      for (int ksl = 0; ksl < 3; ++ksl)
        G[ti] = __builtin_amdgcn_mfma_f32_16x16x32_bf16(AF[(ti * 3 + ksl) * 64 + lane], By[ksl].v, G[ti], 0, 0, 0);
  }
  __syncthreads();
  stageChunk(sB, wsp, WS_W2, 7, 7, 3, 2, tid);
  __syncthreads();
  {
    const bf16x8* AF = (const bf16x8*)sB;
#pragma unroll
    for (int ti = 0; ti < 7; ++ti)
#pragma unroll
      for (int ksl = 0; ksl < 2; ++ksl)
        G[ti] = __builtin_amdgcn_mfma_f32_16x16x32_bf16(AF[(ti * 2 + ksl) * 64 + lane], By[3 + ksl].v, G[ti], 0, 0, 0);
  }
  __syncthreads();
  stageChunk(sB, wsp, WS_W2, 7, 7, 5, 2, tid);
  __syncthreads();
  {
    const bf16x8* AF = (const bf16x8*)sB;
#pragma unroll
    for (int ti = 0; ti < 7; ++ti)
#pragma unroll
      for (int ksl = 0; ksl < 2; ++ksl)
        G[ti] = __builtin_amdgcn_mfma_f32_16x16x32_bf16(AF[(ti * 2 + ksl) * 64 + lane], By[5 + ksl].v, G[ti], 0, 0, 0);
  }

  // ---- FC3: out = W3 . leaky(g) + b3, reduce over lane groups ----
  float pd = 0.f;
#pragma unroll
  for (int ti = 0; ti < 7; ++ti) {
    f32x4 w3 = ((const f32x4*)(sB + L_W3))[ti * 4 + grp];
#pragma unroll
    for (int r = 0; r < 4; ++r) {
      float g = G[ti][r];
      g = fmaxf(g, 0.2f * g);
      pd = fmaf(w3[r], g, pd);
    }
  }
  pd += __shfl_xor(pd, 16);
  pd += __shfl_xor(pd, 32);
  if (lane < 16) out[blockIdx.x * NBB + wid * 16 + lane] = pd + c_b3;
}

extern "C" void kernel_launch(void* const* d_in, const int* in_sizes, int n_in,
                              void* d_out, int out_size, void* d_ws, size_t ws_size,
                              hipStream_t stream)
{
  const int*   dots    = (const int*)d_in[0];
  const float* w_each  = (const float*)d_in[1];
  const float* b_each  = (const float*)d_in[2];
  const float* w_not   = (const float*)d_in[3];
  const float* b_not   = (const float*)d_in[4];
  const float* w_not2  = (const float*)d_in[5];
  const float* b_not2  = (const float*)d_in[6];
  const float* w_empty = (const float*)d_in[7];
  const float* b_empty = (const float*)d_in[8];
  const float* W1 = (const float*)d_in[9];
  const float* b1 = (const float*)d_in[10];
  const float* W2 = (const float*)d_in[11];
  const float* b2 = (const float*)d_in[12];
  const float* W3 = (const float*)d_in[13];
  const float* b3 = (const float*)d_in[14];

  (void)in_sizes; (void)n_in; (void)out_size; (void)ws_size;

  ushort* wsp = (ushort*)d_ws;

  k_setup<<<(WS_TOT + 255) / 256, 256, 0, stream>>>(
      w_each, w_not, w_not2, w_empty, W1, W2, wsp);
  k_main<<<NBLK, NT, 0, stream>>>(
      dots, wsp, b_each, b_not, b_not2, b_empty, b1, b2, W3, b3, (float*)d_out);
}